// Round 1
// baseline (115.553 us; speedup 1.0000x reference)
//
#include <hip/hip_runtime.h>

typedef unsigned int uint32;
typedef unsigned short ushort;

typedef __bf16  bf16x8   __attribute__((ext_vector_type(8)));
typedef float   f32x4    __attribute__((ext_vector_type(4)));
typedef ushort  ushort4v __attribute__((ext_vector_type(4)));
typedef float   float4v  __attribute__((ext_vector_type(4)));

#define K_CODES 1024
#define CDIM    64
#define HWALL   4096      // H*W
#define CHW     262144    // CDIM*HWALL

__device__ __forceinline__ ushort f2bf(float f) {
    uint32 u = __builtin_bit_cast(uint32, f);
    u += 0x7FFFu + ((u >> 16) & 1u);   // RNE; inputs are normal floats
    return (ushort)(u >> 16);
}

// Pass 0: codebook fp32 -> bf16 (row-major [k][c]) + negbias[k] = -0.5*||e_k||^2.
// One wave per code; fully coalesced.
__global__ __launch_bounds__(256) void prep_kernel(const float* __restrict__ cb,
                                                   ushort* __restrict__ cbb,
                                                   float* __restrict__ negbias) {
    int t = threadIdx.x;
    int k = blockIdx.x * 4 + (t >> 6);
    int c = t & 63;
    float v = cb[k * 64 + c];
    cbb[k * 64 + c] = f2bf(v);
    float s = v * v;
    #pragma unroll
    for (int d = 1; d < 64; d <<= 1) s += __shfl_xor(s, d, 64);
    if (c == 0) negbias[k] = -0.5f * s;
}

// Main: 256 blocks (1/CU) x 256 threads. Each block: 256 z-vectors (fixed b, 256
// consecutive hw). Score GEMM via mfma_f32_16x16x32_bf16, argmax epilogue, fused
// vq_out write + loss.
__global__ __launch_bounds__(256, 1) void vq_kernel(const float* __restrict__ z,
                                                    const float* __restrict__ cb,
                                                    const ushort* __restrict__ cbb,
                                                    const float* __restrict__ negbias,
                                                    float* __restrict__ out) {
    // A-tile in MFMA A-layout: [row][k] bf16, row pitch 72 (16B-aligned rows)
    __shared__ __align__(16) ushort Abf[256 * 72];
    __shared__ int idxl[256];

    const int t  = threadIdx.x;
    const int blk = blockIdx.x;
    const int b  = blk >> 4;
    const int hw_base = (blk & 15) << 8;
    const int zoff = b * CHW + hw_base;

    // ---- Phase 1: stage z tile (256 rows x 64 c) to LDS as bf16 ----
    // per instruction: each wave reads 64 consecutive floats (256B) -- coalesced
    #pragma unroll
    for (int it = 0; it < 16; ++it) {
        ushort4v pk;
        #pragma unroll
        for (int j = 0; j < 4; ++j) {
            int c = it * 4 + j;
            pk[j] = f2bf(z[zoff + c * HWALL + t]);
        }
        *(ushort4v*)&Abf[t * 72 + it * 4] = pk;
    }
    __syncthreads();

    // ---- Phase 2: score GEMM + argmax ----
    const int w = t >> 6;    // wave id: owns rows [w*64, w*64+64)
    const int l = t & 63;
    const int m = l & 15;    // A row within m-block / B col within n-tile
    const int q = l >> 4;    // k-quad

    bf16x8 a[4][2];
    #pragma unroll
    for (int mb = 0; mb < 4; ++mb) {
        int row = w * 64 + mb * 16 + m;
        #pragma unroll
        for (int ks = 0; ks < 2; ++ks)
            a[mb][ks] = *(const bf16x8*)&Abf[row * 72 + ks * 32 + q * 8];
    }

    // packed key = (score bits & ~1023) | (1023 - code_idx): v_max_f32 does argmax
    float best[16];
    #pragma unroll
    for (int i = 0; i < 16; ++i) best[i] = -__builtin_inff();

    const ushort* bbase = cbb + q * 8;
    bf16x8 b0c = *(const bf16x8*)(bbase + m * 64);
    bf16x8 b1c = *(const bf16x8*)(bbase + m * 64 + 32);
    float  nbc = negbias[m];

    #pragma unroll 2
    for (int nt = 0; nt < 64; ++nt) {
        // prefetch next n-tile (wraps harmlessly on last iter)
        int coln = (((nt + 1) & 63) << 4) + m;
        bf16x8 b0n = *(const bf16x8*)(bbase + coln * 64);
        bf16x8 b1n = *(const bf16x8*)(bbase + coln * 64 + 32);
        float  nbn = negbias[coln];

        uint32 tag = 1023u - (uint32)((nt << 4) + m);
        f32x4 acc0;
        acc0[0] = nbc; acc0[1] = nbc; acc0[2] = nbc; acc0[3] = nbc;
        #pragma unroll
        for (int mb = 0; mb < 4; ++mb) {
            f32x4 acc = __builtin_amdgcn_mfma_f32_16x16x32_bf16(a[mb][0], b0c, acc0, 0, 0, 0);
            acc       = __builtin_amdgcn_mfma_f32_16x16x32_bf16(a[mb][1], b1c, acc,  0, 0, 0);
            #pragma unroll
            for (int r = 0; r < 4; ++r) {
                uint32 kb = (__builtin_bit_cast(uint32, acc[r]) & 0xFFFFFC00u) | tag;
                best[mb * 4 + r] = fmaxf(best[mb * 4 + r], __builtin_bit_cast(float, kb));
            }
        }
        b0c = b0n; b1c = b1n; nbc = nbn;
    }

    // cross-lane argmax over the 16 lanes sharing q (cols are lane-distributed)
    #pragma unroll
    for (int i = 0; i < 16; ++i) {
        float v = best[i];
        #pragma unroll
        for (int d = 1; d < 16; d <<= 1) v = fmaxf(v, __shfl_xor(v, d, 64));
        best[i] = v;
    }
    if (m == 0) {
        #pragma unroll
        for (int mb = 0; mb < 4; ++mb)
            #pragma unroll
            for (int r = 0; r < 4; ++r) {
                int row = w * 64 + mb * 16 + q * 4 + r;  // C/D: row=(l>>4)*4+reg
                idxl[row] = 1023 - (int)(__builtin_bit_cast(uint32, best[mb * 4 + r]) & 1023u);
            }
    }
    __syncthreads();

    // ---- Phase 3: vq_out writeback (coalesced per c) + fp32 loss ----
    int myidx = idxl[t];
    const float4v* crow = (const float4v*)(cb + myidx * 64);
    float lsum = 0.f;
    #pragma unroll 4
    for (int c4 = 0; c4 < 16; ++c4) {
        float4v e4 = crow[c4];
        #pragma unroll
        for (int j = 0; j < 4; ++j) {
            int c = c4 * 4 + j;
            float zp = z[zoff + c * HWALL + t];   // L2-hot (read in phase 1)
            float vq = e4[j];
            out[1 + zoff + c * HWALL + t] = zp + (vq - zp);  // straight-through
            float d = vq - zp;
            lsum += d * d;
        }
    }
    #pragma unroll
    for (int d = 1; d < 64; d <<= 1) lsum += __shfl_xor(lsum, d, 64);
    if (l == 0) atomicAdd(out, lsum * (1.25f / 4194304.f));  // (1+BETA)/numel
}

extern "C" void kernel_launch(void* const* d_in, const int* in_sizes, int n_in,
                              void* d_out, int out_size, void* d_ws, size_t ws_size,
                              hipStream_t stream) {
    (void)in_sizes; (void)n_in; (void)out_size; (void)ws_size;
    const float* z  = (const float*)d_in[0];
    const float* cb = (const float*)d_in[1];
    float* out = (float*)d_out;
    ushort* cbb = (ushort*)d_ws;
    float* negbias = (float*)((char*)d_ws + K_CODES * CDIM * sizeof(ushort));

    hipMemsetAsync(d_out, 0, sizeof(float), stream);  // loss accumulator
    prep_kernel<<<dim3(256), dim3(256), 0, stream>>>(cb, cbb, negbias);
    vq_kernel<<<dim3(256), dim3(256), 0, stream>>>(z, cb, cbb, negbias, out);
}

// Round 2
// 95.136 us; speedup vs baseline: 1.2146x; 1.2146x over previous
//
#include <hip/hip_runtime.h>

typedef unsigned int uint32;
typedef unsigned short ushort;

typedef __bf16  bf16x8   __attribute__((ext_vector_type(8)));
typedef float   f32x4    __attribute__((ext_vector_type(4)));
typedef ushort  ushort4v __attribute__((ext_vector_type(4)));
typedef float   float4v  __attribute__((ext_vector_type(4)));

#define K_CODES 1024
#define CDIM    64
#define HWALL   4096      // H*W
#define CHW     262144    // CDIM*HWALL

__device__ __forceinline__ ushort f2bf(float f) {
    uint32 u = __builtin_bit_cast(uint32, f);
    u += 0x7FFFu + ((u >> 16) & 1u);   // RNE; inputs are normal floats
    return (ushort)(u >> 16);
}

// Pass 0: codebook fp32 -> bf16 (row-major [k][c]) + negbias[k] = -0.5*||e_k||^2.
// Also zeroes the loss accumulator cell (out[0]) -- replaces a memset dispatch.
__global__ __launch_bounds__(256) void prep_kernel(const float* __restrict__ cb,
                                                   ushort* __restrict__ cbb,
                                                   float* __restrict__ negbias,
                                                   float* __restrict__ out) {
    int t = threadIdx.x;
    if (blockIdx.x == 0 && t == 0) out[0] = 0.f;
    int k = blockIdx.x * 4 + (t >> 6);
    int c = t & 63;
    float v = cb[k * 64 + c];
    cbb[k * 64 + c] = f2bf(v);
    float s = v * v;
    #pragma unroll
    for (int d = 1; d < 64; d <<= 1) s += __shfl_xor(s, d, 64);
    if (c == 0) negbias[k] = -0.5f * s;
}

// Main: 256 blocks (1/CU) x 1024 threads (16 waves = 4 m-groups x 4 n-groups).
// Each block: 256 z-vectors. Wave (mg,ng): rows [mg*64,+64) x n-tiles [ng*16,+16).
// Per-wave B traffic 32 KB -> block total 512 KB (same 128 MB device-wide as the
// round-1 kernel) but 4 waves/SIMD instead of 1.
__global__ __launch_bounds__(1024, 4) void vq_kernel(const float* __restrict__ z,
                                                     const float* __restrict__ cb,
                                                     const ushort* __restrict__ cbb,
                                                     const float* __restrict__ negbias,
                                                     float* __restrict__ out) {
    // A-tile in MFMA A-layout: [row][k] bf16, row pitch 72 (16B-aligned rows)
    __shared__ __align__(16) ushort Abf[256 * 72];
    __shared__ float partial[4][256];   // packed argmax keys per n-group per row
    __shared__ float loss_acc;

    const int t   = threadIdx.x;
    const int blk = blockIdx.x;
    const int b   = blk >> 4;
    const int hw_base = (blk & 15) << 8;
    const int zoff = b * CHW + hw_base;

    if (t == 0) loss_acc = 0.f;

    // ---- Phase 1: stage z tile (256 rows x 64 c) to LDS as bf16 ----
    {
        int r  = t & 255;      // lanes within a wave have consecutive r -> coalesced 256B
        int cg = t >> 8;       // 4 c-groups of 16
        #pragma unroll
        for (int j4 = 0; j4 < 4; ++j4) {
            ushort4v pk;
            #pragma unroll
            for (int j = 0; j < 4; ++j) {
                int c = cg * 16 + j4 * 4 + j;
                pk[j] = f2bf(z[zoff + c * HWALL + r]);
            }
            *(ushort4v*)&Abf[r * 72 + cg * 16 + j4 * 4] = pk;
        }
    }
    __syncthreads();

    // ---- Phase 2: score GEMM + argmax ----
    const int w  = t >> 6;     // wave id 0..15
    const int l  = t & 63;
    const int mg = w & 3;      // m-group: rows [mg*64, +64)
    const int ng = w >> 2;     // n-group: n-tiles [ng*16, +16)
    const int m  = l & 15;     // A row in m-block / B col in n-tile
    const int q  = l >> 4;     // k-quad

    bf16x8 a[4][2];
    #pragma unroll
    for (int mb = 0; mb < 4; ++mb) {
        int row = mg * 64 + mb * 16 + m;
        #pragma unroll
        for (int ks = 0; ks < 2; ++ks)
            a[mb][ks] = *(const bf16x8*)&Abf[row * 72 + ks * 32 + q * 8];
    }

    // packed key = (score bits & ~1023) | (1023 - code_idx): v_max_f32 does argmax
    float best[16];
    #pragma unroll
    for (int i = 0; i < 16; ++i) best[i] = -__builtin_inff();

    const ushort* bbase = cbb + q * 8;
    {
        int col0 = (ng << 8) + m;          // nt = ng*16 -> col = nt*16 + m
        bf16x8 b0c = *(const bf16x8*)(bbase + col0 * 64);
        bf16x8 b1c = *(const bf16x8*)(bbase + col0 * 64 + 32);
        float  nbc = negbias[col0];

        #pragma unroll 2
        for (int ntl = 0; ntl < 16; ++ntl) {
            int nt = ng * 16 + ntl;
            // prefetch next n-tile (wrap keeps it in-bounds on the last iter)
            int coln = ((((nt + 1) & 63) << 4)) + m;
            bf16x8 b0n = *(const bf16x8*)(bbase + coln * 64);
            bf16x8 b1n = *(const bf16x8*)(bbase + coln * 64 + 32);
            float  nbn = negbias[coln];

            uint32 tag = 1023u - (uint32)((nt << 4) + m);
            f32x4 acc0;
            acc0[0] = nbc; acc0[1] = nbc; acc0[2] = nbc; acc0[3] = nbc;
            #pragma unroll
            for (int mb = 0; mb < 4; ++mb) {
                f32x4 acc = __builtin_amdgcn_mfma_f32_16x16x32_bf16(a[mb][0], b0c, acc0, 0, 0, 0);
                acc       = __builtin_amdgcn_mfma_f32_16x16x32_bf16(a[mb][1], b1c, acc,  0, 0, 0);
                #pragma unroll
                for (int r = 0; r < 4; ++r) {
                    uint32 kb = (__builtin_bit_cast(uint32, acc[r]) & 0xFFFFFC00u) | tag;
                    best[mb * 4 + r] = fmaxf(best[mb * 4 + r], __builtin_bit_cast(float, kb));
                }
            }
            b0c = b0n; b1c = b1n; nbc = nbn;
        }
    }

    // cross-lane argmax over the 16 lanes sharing q (cols are lane-distributed)
    #pragma unroll
    for (int i = 0; i < 16; ++i) {
        float v = best[i];
        #pragma unroll
        for (int d = 1; d < 16; d <<= 1) v = fmaxf(v, __shfl_xor(v, d, 64));
        best[i] = v;
    }
    if (m == 0) {     // 4 lanes (q=0..3) x 16 entries each
        #pragma unroll
        for (int mb = 0; mb < 4; ++mb)
            #pragma unroll
            for (int r = 0; r < 4; ++r) {
                int row = mg * 64 + mb * 16 + q * 4 + r;  // C/D: row=(l>>4)*4+reg
                partial[ng][row] = best[mb * 4 + r];
            }
    }
    __syncthreads();

    // ---- Phase 3: combine n-groups, vq_out writeback (coalesced per c) + loss ----
    {
        int r  = t & 255;
        int cg = t >> 8;
        float km = fmaxf(fmaxf(partial[0][r], partial[1][r]),
                         fmaxf(partial[2][r], partial[3][r]));
        int idx = 1023 - (int)(__builtin_bit_cast(uint32, km) & 1023u);

        const float4v* crow = (const float4v*)(cb + idx * 64);
        float lsum = 0.f;
        #pragma unroll
        for (int j4 = 0; j4 < 4; ++j4) {
            float4v e4 = crow[cg * 4 + j4];
            #pragma unroll
            for (int j = 0; j < 4; ++j) {
                int c = cg * 16 + j4 * 4 + j;
                float zp = z[zoff + c * HWALL + r];    // L2-hot (read in phase 1)
                float vq = e4[j];
                out[1 + zoff + c * HWALL + r] = vq;    // straight-through fwd == vq
                float d = vq - zp;
                lsum += d * d;
            }
        }
        #pragma unroll
        for (int d = 1; d < 64; d <<= 1) lsum += __shfl_xor(lsum, d, 64);
        if (l == 0) atomicAdd(&loss_acc, lsum);
    }
    __syncthreads();
    if (t == 0) atomicAdd(out, loss_acc * (1.25f / 4194304.f));  // (1+BETA)/numel
}

extern "C" void kernel_launch(void* const* d_in, const int* in_sizes, int n_in,
                              void* d_out, int out_size, void* d_ws, size_t ws_size,
                              hipStream_t stream) {
    (void)in_sizes; (void)n_in; (void)out_size; (void)ws_size;
    const float* z  = (const float*)d_in[0];
    const float* cb = (const float*)d_in[1];
    float* out = (float*)d_out;
    ushort* cbb = (ushort*)d_ws;
    float* negbias = (float*)((char*)d_ws + K_CODES * CDIM * sizeof(ushort));

    prep_kernel<<<dim3(256), dim3(256), 0, stream>>>(cb, cbb, negbias, out);
    vq_kernel<<<dim3(256), dim3(1024), 0, stream>>>(z, cb, cbb, negbias, out);
}